// Round 1
// baseline (33.531 us; speedup 1.0000x reference)
//
#include <hip/hip_runtime.h>

#define N_TOK 512
#define LATOMS 3072
#define NBATCH 2
#define BOND_CUTOFF 2.4f
#define BLOCK 256

// One block per row a1. Threads stride over a2 for both batches.
// Partials (double sum, u64 count) written per-row to workspace.
__global__ __launch_bounds__(BLOCK) void plbl_row_kernel(
    const int* __restrict__ is_ligand,      // [N_TOK]
    const int* __restrict__ token_bonds,    // [N_TOK*N_TOK]
    const int* __restrict__ tokmap,         // [LATOMS]
    const int* __restrict__ crd_mask,       // [NBATCH*LATOMS]
    const float* __restrict__ X,            // [NBATCH*LATOMS*3]
    const float* __restrict__ Xgt,          // [NBATCH*LATOMS*3]
    double* __restrict__ ws_sum,            // [LATOMS]
    unsigned long long* __restrict__ ws_cnt)// [LATOMS]
{
    const int a1 = blockIdx.x;
    const int t  = threadIdx.x;

    const int ta1  = tokmap[a1];
    const int lig1 = is_ligand[ta1];
    const int m1b0 = crd_mask[0 * LATOMS + a1];
    const int m1b1 = crd_mask[1 * LATOMS + a1];

    // Uniform (block-wide) early exit: row contributes nothing.
    if (!lig1 || !(m1b0 | m1b1)) {
        if (t == 0) { ws_sum[a1] = 0.0; ws_cnt[a1] = 0ULL; }
        return;
    }

    const int* __restrict__ bondrow = token_bonds + (size_t)ta1 * N_TOK;

    // Row-constant coordinates (per batch).
    const float p0x = X[(0 * LATOMS + a1) * 3 + 0];
    const float p0y = X[(0 * LATOMS + a1) * 3 + 1];
    const float p0z = X[(0 * LATOMS + a1) * 3 + 2];
    const float p1x = X[(1 * LATOMS + a1) * 3 + 0];
    const float p1y = X[(1 * LATOMS + a1) * 3 + 1];
    const float p1z = X[(1 * LATOMS + a1) * 3 + 2];

    const float g0x = Xgt[(0 * LATOMS + a1) * 3 + 0];
    const float g0y = Xgt[(0 * LATOMS + a1) * 3 + 1];
    const float g0z = Xgt[(0 * LATOMS + a1) * 3 + 2];
    const float g1x = Xgt[(1 * LATOMS + a1) * 3 + 0];
    const float g1y = Xgt[(1 * LATOMS + a1) * 3 + 1];
    const float g1z = Xgt[(1 * LATOMS + a1) * 3 + 2];

    double acc = 0.0;
    unsigned int cnt = 0;

    for (int a2 = t; a2 < LATOMS; a2 += BLOCK) {
        const int ta2 = tokmap[a2];
        if (is_ligand[ta2]) continue;          // need !is_ligand[col]
        if (!bondrow[ta2]) continue;           // token bond required

        // Batch 0
        if (m1b0 && crd_mask[0 * LATOMS + a2]) {
            const float qx = X[(0 * LATOMS + a2) * 3 + 0];
            const float qy = X[(0 * LATOMS + a2) * 3 + 1];
            const float qz = X[(0 * LATOMS + a2) * 3 + 2];
            const float hx = Xgt[(0 * LATOMS + a2) * 3 + 0];
            const float hy = Xgt[(0 * LATOMS + a2) * 3 + 1];
            const float hz = Xgt[(0 * LATOMS + a2) * 3 + 2];
            const float dgx = g0x - hx, dgy = g0y - hy, dgz = g0z - hz;
            const float gt2 = dgx * dgx + dgy * dgy + dgz * dgz;
            const float gt  = sqrtf(gt2);
            if (gt < BOND_CUTOFF) {
                const float dpx = p0x - qx, dpy = p0y - qy, dpz = p0z - qz;
                const float pr2 = dpx * dpx + dpy * dpy + dpz * dpz;
                const float pr  = sqrtf(pr2);
                const float d   = pr - gt;
                acc += (double)(d * d);
                cnt++;
            }
        }

        // Batch 1
        if (m1b1 && crd_mask[1 * LATOMS + a2]) {
            const float qx = X[(1 * LATOMS + a2) * 3 + 0];
            const float qy = X[(1 * LATOMS + a2) * 3 + 1];
            const float qz = X[(1 * LATOMS + a2) * 3 + 2];
            const float hx = Xgt[(1 * LATOMS + a2) * 3 + 0];
            const float hy = Xgt[(1 * LATOMS + a2) * 3 + 1];
            const float hz = Xgt[(1 * LATOMS + a2) * 3 + 2];
            const float dgx = g1x - hx, dgy = g1y - hy, dgz = g1z - hz;
            const float gt2 = dgx * dgx + dgy * dgy + dgz * dgz;
            const float gt  = sqrtf(gt2);
            if (gt < BOND_CUTOFF) {
                const float dpx = p1x - qx, dpy = p1y - qy, dpz = p1z - qz;
                const float pr2 = dpx * dpx + dpy * dpy + dpz * dpz;
                const float pr  = sqrtf(pr2);
                const float d   = pr - gt;
                acc += (double)(d * d);
                cnt++;
            }
        }
    }

    // Block reduction (deterministic tree).
    __shared__ double s_sum[BLOCK];
    __shared__ unsigned int s_cnt[BLOCK];
    s_sum[t] = acc;
    s_cnt[t] = cnt;
    __syncthreads();
    for (int s = BLOCK / 2; s > 0; s >>= 1) {
        if (t < s) {
            s_sum[t] += s_sum[t + s];
            s_cnt[t] += s_cnt[t + s];
        }
        __syncthreads();
    }
    if (t == 0) {
        ws_sum[a1] = s_sum[0];
        ws_cnt[a1] = (unsigned long long)s_cnt[0];
    }
}

__global__ __launch_bounds__(BLOCK) void plbl_finalize_kernel(
    const double* __restrict__ ws_sum,
    const unsigned long long* __restrict__ ws_cnt,
    float* __restrict__ out)
{
    const int t = threadIdx.x;
    double a = 0.0;
    unsigned long long c = 0ULL;
    for (int i = t; i < LATOMS; i += BLOCK) {
        a += ws_sum[i];
        c += ws_cnt[i];
    }
    __shared__ double s_sum[BLOCK];
    __shared__ unsigned long long s_cnt[BLOCK];
    s_sum[t] = a;
    s_cnt[t] = c;
    __syncthreads();
    for (int s = BLOCK / 2; s > 0; s >>= 1) {
        if (t < s) {
            s_sum[t] += s_sum[t + s];
            s_cnt[t] += s_cnt[t + s];
        }
        __syncthreads();
    }
    if (t == 0) {
        const unsigned long long cc = s_cnt[0] ? s_cnt[0] : 1ULL;
        const float loss = (float)(s_sum[0] / (double)cc);
        out[0] = loss;   // WEIGHT * loss, WEIGHT == 1.0
        out[1] = loss;
    }
}

extern "C" void kernel_launch(void* const* d_in, const int* in_sizes, int n_in,
                              void* d_out, int out_size, void* d_ws, size_t ws_size,
                              hipStream_t stream) {
    const int*   is_ligand   = (const int*)d_in[0];
    const int*   token_bonds = (const int*)d_in[1];
    const int*   tokmap      = (const int*)d_in[2];
    const int*   crd_mask    = (const int*)d_in[3];
    const float* X           = (const float*)d_in[4];
    const float* Xgt         = (const float*)d_in[5];
    float* out = (float*)d_out;

    double* ws_sum = (double*)d_ws;
    unsigned long long* ws_cnt =
        (unsigned long long*)((char*)d_ws + (size_t)LATOMS * sizeof(double));

    plbl_row_kernel<<<LATOMS, BLOCK, 0, stream>>>(
        is_ligand, token_bonds, tokmap, crd_mask, X, Xgt, ws_sum, ws_cnt);
    plbl_finalize_kernel<<<1, BLOCK, 0, stream>>>(ws_sum, ws_cnt, out);
}